// Round 4
// baseline (1248.572 us; speedup 1.0000x reference)
//
#include <hip/hip_runtime.h>

typedef __bf16 bf16;
typedef __bf16 bf16x8 __attribute__((ext_vector_type(8)));
typedef __bf16 bf16x4 __attribute__((ext_vector_type(4)));
typedef float f32x4 __attribute__((ext_vector_type(4)));
typedef unsigned short u16x4 __attribute__((ext_vector_type(4)));
typedef __attribute__((address_space(3))) const void as3_void;

#define GLOAD16(G,L) __builtin_amdgcn_global_load_lds((__attribute__((address_space(1))) const void*)(G), (__attribute__((address_space(3))) void*)(L), 16, 0, 0)

// ---------------- conversion kernels ----------------
__global__ void k_cvt_bf16(const float* __restrict__ src, bf16* __restrict__ dst, int n4){
  int i = blockIdx.x*256 + threadIdx.x;
  if (i < n4){
    float4 v = reinterpret_cast<const float4*>(src)[i];
    bf16x4 o; o[0]=(bf16)v.x; o[1]=(bf16)v.y; o[2]=(bf16)v.z; o[3]=(bf16)v.w;
    reinterpret_cast<bf16x4*>(dst)[i] = o;
  }
}

// src: K x N (f32) -> dst: N x K (bf16)
__global__ void k_transpose_cvt(const float* __restrict__ src, bf16* __restrict__ dst, int K, int N){
  __shared__ float tile[32][33];
  int n0 = blockIdx.x*32, k0 = blockIdx.y*32;
  int tx = threadIdx.x & 31, ty = threadIdx.x >> 5; // 32 x 8
  #pragma unroll
  for (int i=0;i<32;i+=8)
    tile[ty+i][tx] = src[(size_t)(k0+ty+i)*N + n0+tx];
  __syncthreads();
  #pragma unroll
  for (int i=0;i<32;i+=8)
    dst[(size_t)(n0+ty+i)*K + k0+tx] = (bf16)tile[tx][ty+i];
}

// ---------------- 128x128 bf16 MFMA GEMM (m97 structure: global_load_lds + dbuf) ----------------
template<int EPI>
__global__ __launch_bounds__(256,2) void k_gemm(
    const bf16* __restrict__ A, const bf16* __restrict__ Bt,
    const float* __restrict__ bias, int N, int K,
    bf16* __restrict__ q_out, bf16* __restrict__ k_out, bf16* __restrict__ v_out,
    float* __restrict__ c_out)
{
  __shared__ bf16 As[2][128*32];
  __shared__ bf16 Bs[2][128*32];
  const int t = threadIdx.x, w = t>>6, l = t&63, g = l>>4;
  const int nb = N>>7;
  const int m0 = (blockIdx.x / nb)<<7, n0 = (blockIdx.x % nb)<<7;
  const bf16* Ab = A  + (size_t)m0*K;
  const bf16* Bb = Bt + (size_t)n0*K;
  size_t sOff[2];
  #pragma unroll
  for (int j=0;j<2;j++){
    int slot = t + (j<<8);
    sOff[j] = (size_t)(slot>>2)*K + ((slot&3)<<3);
  }
  auto stage = [&](int k0, int buf){
    char* ad = (char*)As + (buf<<13) + (w<<10);
    char* bd = (char*)Bs + (buf<<13) + (w<<10);
    #pragma unroll
    for (int j=0;j<2;j++){
      GLOAD16(Ab + sOff[j] + k0, ad + (j<<12));
      GLOAD16(Bb + sOff[j] + k0, bd + (j<<12));
    }
  };
  f32x4 acc[4][4] = {};
  const int mw = (w&1)<<6, nw = (w>>1)<<6;
  const int nk = K>>5;
  int buf = 0;
  stage(0, 0);
  asm volatile("s_waitcnt vmcnt(0)" ::: "memory");
  __syncthreads();
  for (int ks=0; ks<nk; ++ks){
    if (ks+1 < nk) stage((ks+1)<<5, buf^1);
    bf16x8 af[4], bfm[4];
    #pragma unroll
    for (int mf=0;mf<4;mf++)
      af[mf] = *reinterpret_cast<const bf16x8*>(&As[buf][(mw + mf*16 + (l&15))*32 + (g<<3)]);
    #pragma unroll
    for (int nf=0;nf<4;nf++)
      bfm[nf] = *reinterpret_cast<const bf16x8*>(&Bs[buf][(nw + nf*16 + (l&15))*32 + (g<<3)]);
    #pragma unroll
    for (int mf=0;mf<4;mf++)
      #pragma unroll
      for (int nf=0;nf<4;nf++)
        acc[mf][nf] = __builtin_amdgcn_mfma_f32_16x16x32_bf16(af[mf], bfm[nf], acc[mf][nf], 0,0,0);
    asm volatile("s_waitcnt vmcnt(0)" ::: "memory");
    __syncthreads();
    buf ^= 1;
  }
  if constexpr (EPI==0){
    #pragma unroll
    for (int nf=0;nf<4;nf++){
      const int col = n0 + nw + nf*16 + (l&15);
      const int sec = col>>11; const int rem = col&2047;
      const int hh = rem>>7;  const int dd = rem&127;
      bf16* dst = (sec==0) ? q_out : ((sec==1) ? k_out : v_out);
      const float bv = bias[col];
      #pragma unroll
      for (int mf=0;mf<4;mf++)
        #pragma unroll
        for (int ri=0;ri<4;ri++){
          const int row = m0 + mw + mf*16 + (g<<2) + ri;
          const int bb = row>>10, qp = row&1023;
          dst[(((size_t)(bb*16+hh)*1024 + qp)<<7) + dd] = (bf16)(acc[mf][nf][ri] + bv);
        }
    }
  } else {
    #pragma unroll
    for (int nf=0;nf<4;nf++){
      const int col = n0 + nw + nf*16 + (l&15);
      const float bv = bias[col];
      #pragma unroll
      for (int mf=0;mf<4;mf++)
        #pragma unroll
        for (int ri=0;ri<4;ri++){
          const int row = m0 + mw + mf*16 + (g<<2) + ri;
          c_out[(size_t)row*N + col] = acc[mf][nf][ri] + bv;
        }
    }
  }
}

// ---------------- fused paged + causal flash attention ----------------
// block = (b, h, 256-row q-tile); 8 waves x 32 q-rows (mq=2 x 16). 512 blocks, 2/CU -> 4 waves/SIMD.
// Swapped QK^T: S^T = mfma(K, Q); V pi-permuted subtiled LDS -> tr_read B-frags; softmax in log2 domain.
__global__ __launch_bounds__(512,4) void k_attn(
    const bf16* __restrict__ qb, const bf16* __restrict__ kb, const bf16* __restrict__ vb,
    const bf16* __restrict__ kpb, const bf16* __restrict__ vpb,
    const int* __restrict__ page_pos, const int* __restrict__ input_pos,
    bf16* __restrict__ ctx)
{
  __shared__ bf16 Ks[2*64*128];   // [buf][kv][d] row-major, XOR-swizzled (swz on read, inv-swz source)
  __shared__ bf16 Vs[2*64*128];   // [buf] subtiled for ds_read_b64_tr_b16, rows pi-permuted
  const int t = threadIdx.x, w = t>>6, l = t&63, g = l>>4, c = l&15;
  const int bid = blockIdx.x;
  const int wg = (bid&7)*64 + (bid>>3);   // XCD swizzle, nwg=512 (512%8==0)
  const int qt = wg & 3, h = (wg>>2)&15, b = wg>>6;
  const int q0w = (qt<<8) + (w<<5);
  const float scale2 = 0.12751743f; // (1/sqrt(128)) * log2(e)
  const size_t bh = (size_t)(b*16 + h);

  const bf16* qptr = qb + (bh<<17);
  bf16x8 qf[2][4];
  #pragma unroll
  for (int mq=0;mq<2;mq++)
    #pragma unroll
    for (int kc=0;kc<4;kc++)
      qf[mq][kc] = *reinterpret_cast<const bf16x8*>(qptr + ((size_t)(q0w + mq*16 + c)<<7) + kc*32 + (g<<3));

  int kOff[2], vOff[2];
  #pragma unroll
  for (int j=0;j<2;j++){
    const int slot = t + (j<<9);
    { // K: linear LDS dest; source inverse-swizzled so swizzled reads see row-major
      const int a = slot<<4; const int r = a>>8; const int co = (a&255) ^ ((r&7)<<4);
      kOff[j] = (r<<7) + (co>>1);
    }
    { // V: subtiled dest; slot s covers u={2s,2s+1}
      const int s_ = slot;
      const int p  = ((s_>>6)<<2) | ((s_>>1)&3);
      const int d0 = (((s_>>3)&7)<<4) | ((s_&1)<<3);
      const int pp = (p&32) | ((p&4)<<2) | (((p>>3)&3)<<2) | (p&3); // pi(p)
      vOff[j] = (pp<<7) + d0;
    }
  }
  const bf16* kcb = kb + (bh<<17);
  const bf16* vcb = vb + (bh<<17);
  const int len_b = input_pos[b*2+1];
  const int NT = 32 + ((qt+1)<<2);

  f32x4 o[2][8] = {};
  float mrow[2] = {-1e38f,-1e38f};   // log2 domain
  float lsum[2] = {0.f,0.f};

  auto tsrc = [&](int T, const bf16*& ks, const bf16*& vs_){
    if (T < 32){
      size_t pb = ((((size_t)(T>>2)<<3) + (size_t)b)*16 + (size_t)h) << 15;
      size_t off = (size_t)(T&3)<<13;
      ks = kpb + pb + off; vs_ = vpb + pb + off;
    } else {
      int kt = T-32; ks = kcb + ((size_t)kt<<13); vs_ = vcb + ((size_t)kt<<13);
    }
  };
  auto stage = [&](int T, int buf){
    const bf16 *ks, *vs_; tsrc(T, ks, vs_);
    char* kd = (char*)Ks + (buf<<14) + (w<<10);
    char* vd = (char*)Vs + (buf<<14) + (w<<10);
    #pragma unroll
    for (int j=0;j<2;j++){
      GLOAD16(ks  + kOff[j], kd + (j<<13));
      GLOAD16(vs_ + vOff[j], vd + (j<<13));
    }
  };

  auto process = [&](int buf, int lo, int hi, bool masked, bool causal, int ktg){
    const char* Kb = (const char*)Ks + (buf<<14);
    const char* Vb = (const char*)Vs + (buf<<14);
    // QK^T (swapped): s[cb][mq], lane: q = q0w+mq*16+c, kv = cb*16 + 4g + ri
    f32x4 s[4][2] = {{},{},{},{}};
    #pragma unroll
    for (int kc=0;kc<4;kc++){
      bf16x8 kf[4];
      #pragma unroll
      for (int cb=0;cb<4;cb++){
        const int krow = (cb<<4) + c;
        unsigned a = (unsigned)((krow<<8) + (kc<<6) + (g<<4)); a ^= (unsigned)((krow&7)<<4);
        kf[cb] = *reinterpret_cast<const bf16x8*>(Kb + a);
      }
      __builtin_amdgcn_s_setprio(1);
      #pragma unroll
      for (int cb=0;cb<4;cb++)
        #pragma unroll
        for (int mq=0;mq<2;mq++)
          s[cb][mq] = __builtin_amdgcn_mfma_f32_16x16x32_bf16(kf[cb], qf[mq][kc], s[cb][mq], 0,0,0);
      __builtin_amdgcn_s_setprio(0);
    }
    // scale (log2 domain) + optional mask
    if (masked){
      #pragma unroll
      for (int cb=0;cb<4;cb++)
        #pragma unroll
        for (int ri=0;ri<4;ri++){
          const int kvl = (cb<<4) + (g<<2) + ri;
          const bool vok = (kvl >= lo) && (kvl < hi);
          #pragma unroll
          for (int mq=0;mq<2;mq++){
            bool ok = vok;
            if (causal) ok = ok && ((ktg + kvl) <= (q0w + mq*16 + c));
            s[cb][mq][ri] = ok ? s[cb][mq][ri]*scale2 : -3e38f;
          }
        }
    } else {
      #pragma unroll
      for (int cb=0;cb<4;cb++)
        #pragma unroll
        for (int mq=0;mq<2;mq++)
          #pragma unroll
          for (int ri=0;ri<4;ri++)
            s[cb][mq][ri] *= scale2;
    }
    // online softmax (log2 domain) with defer-max (T13, THR=11.5 bits)
    #pragma unroll
    for (int mq=0;mq<2;mq++){
      float mx = -3e38f;
      #pragma unroll
      for (int cb=0;cb<4;cb++)
        #pragma unroll
        for (int ri=0;ri<4;ri++) mx = fmaxf(mx, s[cb][mq][ri]);
      mx = fmaxf(mx, __shfl_xor(mx, 16, 64));
      mx = fmaxf(mx, __shfl_xor(mx, 32, 64));
      const int defer = __all(mx - mrow[mq] <= 11.5f);
      if (!defer){
        const float mn = fmaxf(mrow[mq], mx);
        const float al = exp2f(mrow[mq] - mn);
        mrow[mq] = mn;
        lsum[mq] *= al;
        #pragma unroll
        for (int ri=0;ri<4;ri++){
          const float av = __shfl(al, (l&48) | ((g<<2)+ri), 64);
          #pragma unroll
          for (int dcb=0;dcb<8;dcb++) o[mq][dcb][ri] *= av;
        }
      }
      float ps = 0.f;
      #pragma unroll
      for (int cb=0;cb<4;cb++)
        #pragma unroll
        for (int ri=0;ri<4;ri++){
          const float e = exp2f(s[cb][mq][ri] - mrow[mq]);
          s[cb][mq][ri] = e; ps += e;
        }
      lsum[mq] += ps;
    }
    // PV: per-kc batched tr_reads (issue 16, wait once), A-frag from registers
    #pragma unroll
    for (int kc=0;kc<2;kc++){
      u16x4 vr0[8], vr1[8];
      #pragma unroll
      for (int dcb=0;dcb<8;dcb++){
        const unsigned sub = ((unsigned)((((kc<<3) + (g<<1))<<3) + dcb)<<7) + ((unsigned)c<<3);
        as3_void* pl = (as3_void*)(Vb + sub);
        asm volatile("ds_read_b64_tr_b16 %0, %2 offset:0\n\t"
                     "ds_read_b64_tr_b16 %1, %2 offset:1024"
                     : "=&v"(vr0[dcb]), "=&v"(vr1[dcb]) : "v"(pl) : "memory");
      }
      bf16x8 pav[2];
      #pragma unroll
      for (int mq=0;mq<2;mq++)
        #pragma unroll
        for (int e=0;e<8;e++)
          pav[mq][e] = (bf16)s[(kc<<1)+(e>>2)][mq][e&3];
      asm volatile("s_waitcnt lgkmcnt(0)" ::: "memory");
      __builtin_amdgcn_sched_barrier(0);
      __builtin_amdgcn_s_setprio(1);
      #pragma unroll
      for (int dcb=0;dcb<8;dcb++){
        union { unsigned short us[8]; bf16x8 v; } uu;
        #pragma unroll
        for (int i=0;i<4;i++){ uu.us[i]=vr0[dcb][i]; uu.us[4+i]=vr1[dcb][i]; }
        #pragma unroll
        for (int mq=0;mq<2;mq++)
          o[mq][dcb] = __builtin_amdgcn_mfma_f32_16x16x32_bf16(pav[mq], uu.v, o[mq][dcb], 0,0,0);
      }
      __builtin_amdgcn_s_setprio(0);
    }
  };

  // ---- pipelined tile loop: stage(T+1) || process(T) ----
  int buf = 0;
  stage(0, 0);
  asm volatile("s_waitcnt vmcnt(0)" ::: "memory");
  __syncthreads();
  for (int T=0; T<NT; ++T){
    if (T+1 < NT) stage(T+1, buf^1);
    int lo=0, hi=64, ktg=0; bool causal=false, masked=false, skip=false;
    if (T < 32){
      const int pg = T>>2, to = T&3;
      const int start = page_pos[(pg*8+b)*2], plen = page_pos[(pg*8+b)*2+1];
      lo = start - (to<<6); hi = start + plen - (to<<6); if (hi>64) hi=64;
      masked = (lo > 0) || (hi < 64);
      skip = (hi <= 0) || (lo >= 64);
    } else {
      const int kt = T-32; ktg = kt<<6;
      hi = len_b - ktg; if (hi>64) hi=64;
      skip = (ktg > q0w + 31) || (hi <= 0);
      causal = (ktg + 63 > q0w);
      masked = causal || (hi < 64);
    }
    if (!skip) process(buf, lo, hi, masked, causal, ktg);
    asm volatile("s_waitcnt vmcnt(0)" ::: "memory");
    __syncthreads();
    buf ^= 1;
  }

  // ---- epilogue: ctx[b][q][h*128+d] (bf16); q = q0w + mq*16 + 4g + ri, d = dcb*16 + c ----
  #pragma unroll
  for (int mq=0;mq<2;mq++){
    float tl = lsum[mq];
    tl += __shfl_xor(tl, 16, 64);
    tl += __shfl_xor(tl, 32, 64);
    const float inv = 1.f / fmaxf(tl, 1e-9f);
    #pragma unroll
    for (int ri=0;ri<4;ri++){
      const float iv = __shfl(inv, (l&48) | ((g<<2)+ri), 64);
      const int q = q0w + mq*16 + (g<<2) + ri;
      #pragma unroll
      for (int dcb=0;dcb<8;dcb++)
        ctx[(((size_t)(b<<10) + q)<<11) + (h<<7) + (dcb<<4) + c] = (bf16)(o[mq][dcb][ri]*iv);
    }
  }
}

// ---------------- launcher ----------------
extern "C" void kernel_launch(void* const* d_in, const int* in_sizes, int n_in,
                              void* d_out, int out_size, void* d_ws, size_t ws_size,
                              hipStream_t stream)
{
  const float* hidden  = (const float*)d_in[0];
  const float* W_attn  = (const float*)d_in[1];
  const float* b_attn  = (const float*)d_in[2];
  const float* W_proj  = (const float*)d_in[3];
  const float* b_proj  = (const float*)d_in[4];
  const float* k_pages = (const float*)d_in[5];
  const float* v_pages = (const float*)d_in[6];
  const int*   page_pos  = (const int*)d_in[7];
  const int*   input_pos = (const int*)d_in[8];
  float* out = (float*)d_out;
  char* ws = (char*)d_ws;
  bf16* A1  = (bf16*)(ws);              // 8192x2048 bf16 (32MB); reused as ctx
  bf16* Wt1 = (bf16*)(ws + 33554432);   // 6144x2048 bf16 (24MB)
  bf16* Wt2 = (bf16*)(ws + 58720256);   // 2048x2048 bf16 (8MB)
  bf16* qb  = (bf16*)(ws + 67108864);   // [8,16,1024,128] bf16 (32MB)
  bf16* kb  = (bf16*)(ws + 100663296);
  bf16* vb  = (bf16*)(ws + 134217728);
  bf16* kpb = (bf16*)(ws + 167772160);  // bf16 pages (64MB)
  bf16* vpb = (bf16*)(ws + 234881024);  // bf16 pages (64MB); end 301,989,888
  bf16* ctx = A1;

  k_cvt_bf16<<<16384, 256, 0, stream>>>(hidden, A1, 4194304);
  k_cvt_bf16<<<32768, 256, 0, stream>>>(k_pages, kpb, 8388608);
  k_cvt_bf16<<<32768, 256, 0, stream>>>(v_pages, vpb, 8388608);
  k_transpose_cvt<<<dim3(192,64), 256, 0, stream>>>(W_attn, Wt1, 2048, 6144);
  k_transpose_cvt<<<dim3(64,64),  256, 0, stream>>>(W_proj, Wt2, 2048, 2048);
  k_gemm<0><<<64*48, 256, 0, stream>>>(A1, Wt1, b_attn, 6144, 2048, qb, kb, vb, nullptr);
  k_attn<<<512, 512, 0, stream>>>(qb, kb, vb, kpb, vpb, page_pos, input_pos, ctx);
  k_gemm<1><<<64*16, 256, 0, stream>>>(ctx, Wt2, b_proj, 2048, 2048, nullptr, nullptr, nullptr, out);
}

// Round 5
// 768.624 us; speedup vs baseline: 1.6244x; 1.6244x over previous
//
#include <hip/hip_runtime.h>

typedef __bf16 bf16;
typedef __bf16 bf16x8 __attribute__((ext_vector_type(8)));
typedef __bf16 bf16x4 __attribute__((ext_vector_type(4)));
typedef float f32x4 __attribute__((ext_vector_type(4)));
typedef unsigned short u16x4 __attribute__((ext_vector_type(4)));
typedef __attribute__((address_space(3))) const void as3_void;

#define GLOAD16(G,L) __builtin_amdgcn_global_load_lds((__attribute__((address_space(1))) const void*)(G), (__attribute__((address_space(3))) void*)(L), 16, 0, 0)

// ---------------- conversion kernels ----------------
__global__ void k_cvt_bf16(const float* __restrict__ src, bf16* __restrict__ dst, int n4){
  int i = blockIdx.x*256 + threadIdx.x;
  if (i < n4){
    float4 v = reinterpret_cast<const float4*>(src)[i];
    bf16x4 o; o[0]=(bf16)v.x; o[1]=(bf16)v.y; o[2]=(bf16)v.z; o[3]=(bf16)v.w;
    reinterpret_cast<bf16x4*>(dst)[i] = o;
  }
}

// src: K x N (f32) -> dst: N x K (bf16)
__global__ void k_transpose_cvt(const float* __restrict__ src, bf16* __restrict__ dst, int K, int N){
  __shared__ float tile[32][33];
  int n0 = blockIdx.x*32, k0 = blockIdx.y*32;
  int tx = threadIdx.x & 31, ty = threadIdx.x >> 5; // 32 x 8
  #pragma unroll
  for (int i=0;i<32;i+=8)
    tile[ty+i][tx] = src[(size_t)(k0+ty+i)*N + n0+tx];
  __syncthreads();
  #pragma unroll
  for (int i=0;i<32;i+=8)
    dst[(size_t)(n0+ty+i)*K + k0+tx] = (bf16)tile[tx][ty+i];
}

// ---------------- 128x128 bf16 MFMA GEMM (m97 structure: global_load_lds + dbuf) ----------------
template<int EPI>
__global__ __launch_bounds__(256,2) void k_gemm(
    const bf16* __restrict__ A, const bf16* __restrict__ Bt,
    const float* __restrict__ bias, int N, int K,
    bf16* __restrict__ q_out, bf16* __restrict__ k_out, bf16* __restrict__ v_out,
    float* __restrict__ c_out)
{
  __shared__ bf16 As[2][128*32];
  __shared__ bf16 Bs[2][128*32];
  const int t = threadIdx.x, w = t>>6, l = t&63, g = l>>4;
  const int nb = N>>7;
  const int m0 = (blockIdx.x / nb)<<7, n0 = (blockIdx.x % nb)<<7;
  const bf16* Ab = A  + (size_t)m0*K;
  const bf16* Bb = Bt + (size_t)n0*K;
  size_t sOff[2];
  #pragma unroll
  for (int j=0;j<2;j++){
    int slot = t + (j<<8);
    sOff[j] = (size_t)(slot>>2)*K + ((slot&3)<<3);
  }
  auto stage = [&](int k0, int buf){
    char* ad = (char*)As + (buf<<13) + (w<<10);
    char* bd = (char*)Bs + (buf<<13) + (w<<10);
    #pragma unroll
    for (int j=0;j<2;j++){
      GLOAD16(Ab + sOff[j] + k0, ad + (j<<12));
      GLOAD16(Bb + sOff[j] + k0, bd + (j<<12));
    }
  };
  f32x4 acc[4][4] = {};
  const int mw = (w&1)<<6, nw = (w>>1)<<6;
  const int nk = K>>5;
  int buf = 0;
  stage(0, 0);
  asm volatile("s_waitcnt vmcnt(0)" ::: "memory");
  __syncthreads();
  for (int ks=0; ks<nk; ++ks){
    if (ks+1 < nk) stage((ks+1)<<5, buf^1);
    bf16x8 af[4], bfm[4];
    #pragma unroll
    for (int mf=0;mf<4;mf++)
      af[mf] = *reinterpret_cast<const bf16x8*>(&As[buf][(mw + mf*16 + (l&15))*32 + (g<<3)]);
    #pragma unroll
    for (int nf=0;nf<4;nf++)
      bfm[nf] = *reinterpret_cast<const bf16x8*>(&Bs[buf][(nw + nf*16 + (l&15))*32 + (g<<3)]);
    #pragma unroll
    for (int mf=0;mf<4;mf++)
      #pragma unroll
      for (int nf=0;nf<4;nf++)
        acc[mf][nf] = __builtin_amdgcn_mfma_f32_16x16x32_bf16(af[mf], bfm[nf], acc[mf][nf], 0,0,0);
    asm volatile("s_waitcnt vmcnt(0)" ::: "memory");
    __syncthreads();
    buf ^= 1;
  }
  if constexpr (EPI==0){
    #pragma unroll
    for (int nf=0;nf<4;nf++){
      const int col = n0 + nw + nf*16 + (l&15);
      const int sec = col>>11; const int rem = col&2047;
      const int hh = rem>>7;  const int dd = rem&127;
      bf16* dst = (sec==0) ? q_out : ((sec==1) ? k_out : v_out);
      const float bv = bias[col];
      #pragma unroll
      for (int mf=0;mf<4;mf++)
        #pragma unroll
        for (int ri=0;ri<4;ri++){
          const int row = m0 + mw + mf*16 + (g<<2) + ri;
          const int bb = row>>10, qp = row&1023;
          dst[(((size_t)(bb*16+hh)*1024 + qp)<<7) + dd] = (bf16)(acc[mf][nf][ri] + bv);
        }
    }
  } else {
    #pragma unroll
    for (int nf=0;nf<4;nf++){
      const int col = n0 + nw + nf*16 + (l&15);
      const float bv = bias[col];
      #pragma unroll
      for (int mf=0;mf<4;mf++)
        #pragma unroll
        for (int ri=0;ri<4;ri++){
          const int row = m0 + mw + mf*16 + (g<<2) + ri;
          c_out[(size_t)row*N + col] = acc[mf][nf][ri] + bv;
        }
    }
  }
}

// ---------------- fused paged + causal flash attention ----------------
// block = (b, h, 128-row q-tile); 8 waves x 16 q-rows. 1024 blocks, 2/CU -> 4 waves/SIMD (pinned).
// Swapped QK^T: S^T = mfma(K, Q); V pi-permuted subtiled LDS -> tr_read B-frags; softmax in log2 domain.
__global__ __launch_bounds__(512) __attribute__((amdgpu_waves_per_eu(4,4))) void k_attn(
    const bf16* __restrict__ qb, const bf16* __restrict__ kb, const bf16* __restrict__ vb,
    const bf16* __restrict__ kpb, const bf16* __restrict__ vpb,
    const int* __restrict__ page_pos, const int* __restrict__ input_pos,
    bf16* __restrict__ ctx)
{
  __shared__ bf16 Ks[2*64*128];   // [buf][kv][d] row-major, XOR-swizzled (swz on read, inv-swz source)
  __shared__ bf16 Vs[2*64*128];   // [buf] subtiled for ds_read_b64_tr_b16, rows pi-permuted
  const int t = threadIdx.x, w = t>>6, l = t&63, g = l>>4, c = l&15;
  const int bid = blockIdx.x;
  const int wg = (bid&7)*128 + (bid>>3);   // XCD swizzle, nwg=1024 (1024%8==0)
  const int qt = wg & 7, h = (wg>>3)&15, b = wg>>7;
  const int q0w = (qt<<7) + (w<<4);        // 16 q-rows per wave
  const float scale2 = 0.12751743f; // (1/sqrt(128)) * log2(e)
  const size_t bh = (size_t)(b*16 + h);

  // Q as B-frags: lane holds q = q0w + c, d = kc*32 + g*8 + e
  const bf16* qptr = qb + (bh<<17);
  bf16x8 qf[4];
  #pragma unroll
  for (int kc=0;kc<4;kc++)
    qf[kc] = *reinterpret_cast<const bf16x8*>(qptr + ((size_t)(q0w + c)<<7) + kc*32 + (g<<3));

  int kOff[2], vOff[2];
  #pragma unroll
  for (int j=0;j<2;j++){
    const int slot = t + (j<<9);
    { // K: linear LDS dest; source inverse-swizzled so swizzled reads see row-major
      const int a = slot<<4; const int r = a>>8; const int co = (a&255) ^ ((r&7)<<4);
      kOff[j] = (r<<7) + (co>>1);
    }
    { // V: subtiled dest; slot s covers u={2s,2s+1}
      const int s_ = slot;
      const int p  = ((s_>>6)<<2) | ((s_>>1)&3);
      const int d0 = (((s_>>3)&7)<<4) | ((s_&1)<<3);
      const int pp = (p&32) | ((p&4)<<2) | (((p>>3)&3)<<2) | (p&3); // pi(p)
      vOff[j] = (pp<<7) + d0;
    }
  }
  const bf16* kcb = kb + (bh<<17);
  const bf16* vcb = vb + (bh<<17);
  const int len_b = input_pos[b*2+1];
  const int NT = 32 + ((qt+1)<<1);

  f32x4 o[8] = {};
  float mrow = -1e38f;   // log2 domain
  float lsum = 0.f;

  auto tsrc = [&](int T, const bf16*& ks, const bf16*& vs_){
    if (T < 32){
      size_t pb = ((((size_t)(T>>2)<<3) + (size_t)b)*16 + (size_t)h) << 15;
      size_t off = (size_t)(T&3)<<13;
      ks = kpb + pb + off; vs_ = vpb + pb + off;
    } else {
      int kt = T-32; ks = kcb + ((size_t)kt<<13); vs_ = vcb + ((size_t)kt<<13);
    }
  };
  auto stage = [&](int T, int buf){
    const bf16 *ks, *vs_; tsrc(T, ks, vs_);
    char* kd = (char*)Ks + (buf<<14) + (w<<10);
    char* vd = (char*)Vs + (buf<<14) + (w<<10);
    #pragma unroll
    for (int j=0;j<2;j++){
      GLOAD16(ks  + kOff[j], kd + (j<<13));
      GLOAD16(vs_ + vOff[j], vd + (j<<13));
    }
  };

  auto process = [&](int buf, int lo, int hi, bool masked, bool causal, int ktg){
    const char* Kb = (const char*)Ks + (buf<<14);
    const char* Vb = (const char*)Vs + (buf<<14);
    // QK^T (swapped): lane: q = q0w + c, kv = cb*16 + 4g + ri
    f32x4 s[4] = {};
    #pragma unroll
    for (int kc=0;kc<4;kc++){
      bf16x8 kf[4];
      #pragma unroll
      for (int cb=0;cb<4;cb++){
        const int krow = (cb<<4) + c;
        unsigned a = (unsigned)((krow<<8) + (kc<<6) + (g<<4)); a ^= (unsigned)((krow&7)<<4);
        kf[cb] = *reinterpret_cast<const bf16x8*>(Kb + a);
      }
      __builtin_amdgcn_s_setprio(1);
      #pragma unroll
      for (int cb=0;cb<4;cb++)
        s[cb] = __builtin_amdgcn_mfma_f32_16x16x32_bf16(kf[cb], qf[kc], s[cb], 0,0,0);
      __builtin_amdgcn_s_setprio(0);
    }
    // scale (log2 domain) + optional mask
    if (masked){
      #pragma unroll
      for (int cb=0;cb<4;cb++)
        #pragma unroll
        for (int ri=0;ri<4;ri++){
          const int kvl = (cb<<4) + (g<<2) + ri;
          bool ok = (kvl >= lo) && (kvl < hi);
          if (causal) ok = ok && ((ktg + kvl) <= (q0w + c));
          s[cb][ri] = ok ? s[cb][ri]*scale2 : -3e38f;
        }
    } else {
      #pragma unroll
      for (int cb=0;cb<4;cb++)
        #pragma unroll
        for (int ri=0;ri<4;ri++)
          s[cb][ri] *= scale2;
    }
    // online softmax (log2 domain) with defer-max (T13, THR=11.5 bits)
    {
      float mx = -3e38f;
      #pragma unroll
      for (int cb=0;cb<4;cb++)
        #pragma unroll
        for (int ri=0;ri<4;ri++) mx = fmaxf(mx, s[cb][ri]);
      mx = fmaxf(mx, __shfl_xor(mx, 16, 64));
      mx = fmaxf(mx, __shfl_xor(mx, 32, 64));
      const int defer = __all(mx - mrow <= 11.5f);
      if (!defer){
        const float mn = fmaxf(mrow, mx);
        const float al = exp2f(mrow - mn);
        mrow = mn;
        lsum *= al;
        #pragma unroll
        for (int ri=0;ri<4;ri++){
          const float av = __shfl(al, (l&48) | ((g<<2)+ri), 64);
          #pragma unroll
          for (int dcb=0;dcb<8;dcb++) o[dcb][ri] *= av;
        }
      }
      float ps = 0.f;
      #pragma unroll
      for (int cb=0;cb<4;cb++)
        #pragma unroll
        for (int ri=0;ri<4;ri++){
          const float e = exp2f(s[cb][ri] - mrow);
          s[cb][ri] = e; ps += e;
        }
      lsum += ps;
    }
    // PV: per-kc batched tr_reads (issue 16, wait once), A-frag from registers
    #pragma unroll
    for (int kc=0;kc<2;kc++){
      u16x4 vr0[8], vr1[8];
      #pragma unroll
      for (int dcb=0;dcb<8;dcb++){
        const unsigned sub = ((unsigned)((((kc<<3) + (g<<1))<<3) + dcb)<<7) + ((unsigned)c<<3);
        as3_void* pl = (as3_void*)(Vb + sub);
        asm volatile("ds_read_b64_tr_b16 %0, %2 offset:0\n\t"
                     "ds_read_b64_tr_b16 %1, %2 offset:1024"
                     : "=&v"(vr0[dcb]), "=&v"(vr1[dcb]) : "v"(pl) : "memory");
      }
      bf16x8 pav;
      #pragma unroll
      for (int e=0;e<8;e++)
        pav[e] = (bf16)s[(kc<<1)+(e>>2)][e&3];
      asm volatile("s_waitcnt lgkmcnt(0)" ::: "memory");
      __builtin_amdgcn_sched_barrier(0);
      __builtin_amdgcn_s_setprio(1);
      #pragma unroll
      for (int dcb=0;dcb<8;dcb++){
        union { unsigned short us[8]; bf16x8 v; } uu;
        #pragma unroll
        for (int i=0;i<4;i++){ uu.us[i]=vr0[dcb][i]; uu.us[4+i]=vr1[dcb][i]; }
        o[dcb] = __builtin_amdgcn_mfma_f32_16x16x32_bf16(pav, uu.v, o[dcb], 0,0,0);
      }
      __builtin_amdgcn_s_setprio(0);
    }
  };

  // ---- pipelined tile loop: stage(T+1) || process(T) ----
  int buf = 0;
  stage(0, 0);
  asm volatile("s_waitcnt vmcnt(0)" ::: "memory");
  __syncthreads();
  for (int T=0; T<NT; ++T){
    if (T+1 < NT) stage(T+1, buf^1);
    int lo=0, hi=64, ktg=0; bool causal=false, masked=false, skip=false;
    if (T < 32){
      const int pg = T>>2, to = T&3;
      const int start = page_pos[(pg*8+b)*2], plen = page_pos[(pg*8+b)*2+1];
      lo = start - (to<<6); hi = start + plen - (to<<6); if (hi>64) hi=64;
      masked = (lo > 0) || (hi < 64);
      skip = (hi <= 0) || (lo >= 64);
    } else {
      const int kt = T-32; ktg = kt<<6;
      hi = len_b - ktg; if (hi>64) hi=64;
      skip = (ktg > q0w + 15) || (hi <= 0);
      causal = (ktg + 63 > q0w);
      masked = causal || (hi < 64);
    }
    if (!skip) process(buf, lo, hi, masked, causal, ktg);
    asm volatile("s_waitcnt vmcnt(0)" ::: "memory");
    __syncthreads();
    buf ^= 1;
  }

  // ---- epilogue: ctx[b][q][h*128+d] (bf16); q = q0w + 4g + ri, d = dcb*16 + c ----
  {
    float tl = lsum;
    tl += __shfl_xor(tl, 16, 64);
    tl += __shfl_xor(tl, 32, 64);
    const float inv = 1.f / fmaxf(tl, 1e-9f);
    #pragma unroll
    for (int ri=0;ri<4;ri++){
      const float iv = __shfl(inv, (l&48) | ((g<<2)+ri), 64);
      const int q = q0w + (g<<2) + ri;
      #pragma unroll
      for (int dcb=0;dcb<8;dcb++)
        ctx[(((size_t)(b<<10) + q)<<11) + (h<<7) + (dcb<<4) + c] = (bf16)(o[dcb][ri]*iv);
    }
  }
}

// ---------------- launcher ----------------
extern "C" void kernel_launch(void* const* d_in, const int* in_sizes, int n_in,
                              void* d_out, int out_size, void* d_ws, size_t ws_size,
                              hipStream_t stream)
{
  const float* hidden  = (const float*)d_in[0];
  const float* W_attn  = (const float*)d_in[1];
  const float* b_attn  = (const float*)d_in[2];
  const float* W_proj  = (const float*)d_in[3];
  const float* b_proj  = (const float*)d_in[4];
  const float* k_pages = (const float*)d_in[5];
  const float* v_pages = (const float*)d_in[6];
  const int*   page_pos  = (const int*)d_in[7];
  const int*   input_pos = (const int*)d_in[8];
  float* out = (float*)d_out;
  char* ws = (char*)d_ws;
  bf16* A1  = (bf16*)(ws);              // 8192x2048 bf16 (32MB); reused as ctx
  bf16* Wt1 = (bf16*)(ws + 33554432);   // 6144x2048 bf16 (24MB)
  bf16* Wt2 = (bf16*)(ws + 58720256);   // 2048x2048 bf16 (8MB)
  bf16* qb  = (bf16*)(ws + 67108864);   // [8,16,1024,128] bf16 (32MB)
  bf16* kb  = (bf16*)(ws + 100663296);
  bf16* vb  = (bf16*)(ws + 134217728);
  bf16* kpb = (bf16*)(ws + 167772160);  // bf16 pages (64MB)
  bf16* vpb = (bf16*)(ws + 234881024);  // bf16 pages (64MB); end 301,989,888
  bf16* ctx = A1;

  k_cvt_bf16<<<16384, 256, 0, stream>>>(hidden, A1, 4194304);
  k_cvt_bf16<<<32768, 256, 0, stream>>>(k_pages, kpb, 8388608);
  k_cvt_bf16<<<32768, 256, 0, stream>>>(v_pages, vpb, 8388608);
  k_transpose_cvt<<<dim3(192,64), 256, 0, stream>>>(W_attn, Wt1, 2048, 6144);
  k_transpose_cvt<<<dim3(64,64),  256, 0, stream>>>(W_proj, Wt2, 2048, 2048);
  k_gemm<0><<<64*48, 256, 0, stream>>>(A1, Wt1, b_attn, 6144, 2048, qb, kb, vb, nullptr);
  k_attn<<<1024, 512, 0, stream>>>(qb, kb, vb, kpb, vpb, page_pos, input_pos, ctx);
  k_gemm<1><<<64*16, 256, 0, stream>>>(ctx, Wt2, b_proj, 2048, 2048, nullptr, nullptr, nullptr, out);
}

// Round 6
// 720.153 us; speedup vs baseline: 1.7338x; 1.0673x over previous
//
#include <hip/hip_runtime.h>

typedef __bf16 bf16;
typedef __bf16 bf16x8 __attribute__((ext_vector_type(8)));
typedef __bf16 bf16x4 __attribute__((ext_vector_type(4)));
typedef float f32x4 __attribute__((ext_vector_type(4)));
typedef unsigned short u16x4 __attribute__((ext_vector_type(4)));
typedef __attribute__((address_space(3))) const void as3_void;

#define GLOAD16(G,L) __builtin_amdgcn_global_load_lds((__attribute__((address_space(1))) const void*)(G), (__attribute__((address_space(3))) void*)(L), 16, 0, 0)

// ---------------- conversion kernels ----------------
__global__ void k_cvt_bf16(const float* __restrict__ src, bf16* __restrict__ dst, int n4){
  int i = blockIdx.x*256 + threadIdx.x;
  if (i < n4){
    float4 v = reinterpret_cast<const float4*>(src)[i];
    bf16x4 o; o[0]=(bf16)v.x; o[1]=(bf16)v.y; o[2]=(bf16)v.z; o[3]=(bf16)v.w;
    reinterpret_cast<bf16x4*>(dst)[i] = o;
  }
}

// src: K x N (f32) -> dst: N x K (bf16)
__global__ void k_transpose_cvt(const float* __restrict__ src, bf16* __restrict__ dst, int K, int N){
  __shared__ float tile[32][33];
  int n0 = blockIdx.x*32, k0 = blockIdx.y*32;
  int tx = threadIdx.x & 31, ty = threadIdx.x >> 5; // 32 x 8
  #pragma unroll
  for (int i=0;i<32;i+=8)
    tile[ty+i][tx] = src[(size_t)(k0+ty+i)*N + n0+tx];
  __syncthreads();
  #pragma unroll
  for (int i=0;i<32;i+=8)
    dst[(size_t)(n0+ty+i)*K + k0+tx] = (bf16)tile[tx][ty+i];
}

// ---------------- 256x256 bf16 MFMA GEMM, 8 waves, BK=64, 4-phase K-tile schedule ----------------
// A: MxK row-major, Bt: NxK row-major. EPI==0: qkv split-head epilogue; EPI==1: bias + f32 out.
// LDS: 2 buf x {A0,A1,B0,B1} half-tiles x 16KB = 128KB. XOR-swizzled rows (^((row&7)<<4)),
// staged via global_load_lds with inverse-swizzled source. Raw s_barrier (no vmcnt drain),
// one vmcnt(0) per K-tile after last MFMA cluster.
template<int EPI>
__global__ __launch_bounds__(512,2) void k_gemm8(
    const bf16* __restrict__ A, const bf16* __restrict__ Bt,
    const float* __restrict__ bias, int N, int K,
    bf16* __restrict__ q_out, bf16* __restrict__ k_out, bf16* __restrict__ v_out,
    float* __restrict__ c_out)
{
  __shared__ bf16 S[2][4][8192];   // [buf][A0,A1,B0,B1][128*64]
  const int t = threadIdx.x, w = t>>6, l = t&63, g = l>>4, c = l&15;
  const int wm = w>>2, wn = w&3;   // 2M x 4N waves
  const int nb = N>>8;
  const int cpx = gridDim.x>>3;
  const int swz = (blockIdx.x&7)*cpx + (blockIdx.x>>3);   // XCD swizzle (grid%8==0)
  const int m0 = (swz/nb)<<8, n0 = (swz%nb)<<8;
  const int NK = K>>6;
  const unsigned xorv = (unsigned)((l&7)<<4);

  // staging geometry: thread t covers rows r0 and r0+64 of a half-tile at column col0
  const int r0 = t>>3;
  const int col0 = ((t&7) ^ (r0&7))<<3;

  auto stageA = [&](int kt2){
    #pragma unroll
    for (int hh=0; hh<2; ++hh){
      const bf16* sp = A + (size_t)(m0 + hh*128)*K + (kt2<<6);
      char* dp = (char*)&S[kt2&1][hh][0];
      GLOAD16(sp + (size_t)r0*K + col0,      dp + t*16);
      GLOAD16(sp + (size_t)(r0+64)*K + col0, dp + (t+512)*16);
    }
  };
  auto stageB = [&](int kt2){
    #pragma unroll
    for (int hh=0; hh<2; ++hh){
      const bf16* sp = Bt + (size_t)(n0 + hh*128)*K + (kt2<<6);
      char* dp = (char*)&S[kt2&1][2+hh][0];
      GLOAD16(sp + (size_t)r0*K + col0,      dp + t*16);
      GLOAD16(sp + (size_t)(r0+64)*K + col0, dp + (t+512)*16);
    }
  };

  f32x4 acc[8][4] = {};

  // prologue: stage tile 0 fully, drain, barrier
  stageA(0); stageB(0);
  asm volatile("s_waitcnt vmcnt(0)" ::: "memory");
  __builtin_amdgcn_s_barrier();

  for (int kt=0; kt<NK; ++kt){
    const int bufc = kt&1;
    const char* Ab_ = (const char*)&S[bufc][wm][0];
    const char* Bb_ = (const char*)&S[bufc][2+(wn>>1)][0];
    const bool pre = (kt+1 < NK);
    bf16x8 af[4][2], bfr[2][2];

    auto lda = [&](int mh){
      #pragma unroll
      for (int mf=0; mf<4; ++mf)
        #pragma unroll
        for (int kk=0; kk<2; ++kk)
          af[mf][kk] = *reinterpret_cast<const bf16x8*>(Ab_ +
              (unsigned)((mh*64 + mf*16 + c)*128) + (((unsigned)(kk*64 + g*16)) ^ xorv));
    };
    auto ldb = [&](int nh){
      #pragma unroll
      for (int nf=0; nf<2; ++nf)
        #pragma unroll
        for (int kk=0; kk<2; ++kk)
          bfr[nf][kk] = *reinterpret_cast<const bf16x8*>(Bb_ +
              (unsigned)(((wn&1)*64 + nh*32 + nf*16 + c)*128) + (((unsigned)(kk*64 + g*16)) ^ xorv));
    };
    auto cluster = [&](int mh, int nh){
      __builtin_amdgcn_s_barrier();
      asm volatile("s_waitcnt lgkmcnt(0)" ::: "memory");
      __builtin_amdgcn_sched_barrier(0);
      __builtin_amdgcn_s_setprio(1);
      #pragma unroll
      for (int mf=0; mf<4; ++mf)
        #pragma unroll
        for (int nf=0; nf<2; ++nf)
          #pragma unroll
          for (int kk=0; kk<2; ++kk)
            acc[mh*4+mf][nh*2+nf] =
              __builtin_amdgcn_mfma_f32_16x16x32_bf16(af[mf][kk], bfr[nf][kk], acc[mh*4+mf][nh*2+nf], 0,0,0);
      __builtin_amdgcn_s_setprio(0);
    };

    // qd0: (mh0,nh0) — 12 ds_reads; stage next-tile A halves
    lda(0); ldb(0);
    if (pre) stageA(kt+1);
    cluster(0,0);
    __builtin_amdgcn_s_barrier();
    // qd1: (mh0,nh1) — 4 ds_reads; stage next-tile B halves
    ldb(1);
    if (pre) stageB(kt+1);
    cluster(0,1);
    __builtin_amdgcn_s_barrier();
    // qd2: (mh1,nh1) — 8 ds_reads
    lda(1);
    cluster(1,1);
    __builtin_amdgcn_s_barrier();
    // qd3: (mh1,nh0) — 4 ds_reads; vmcnt(0) after MFMA, before end barrier
    ldb(0);
    cluster(1,0);
    asm volatile("s_waitcnt vmcnt(0)" ::: "memory");
    __builtin_amdgcn_s_barrier();
  }

  // epilogue: D layout col = lane&15 (n), row = g*4+ri (m)
  if constexpr (EPI==0){
    #pragma unroll
    for (int NF=0; NF<4; ++NF){
      const int col = n0 + wn*64 + NF*16 + c;
      const int sec = col>>11; const int rem = col&2047;
      const int hhd = rem>>7;  const int dd = rem&127;
      bf16* dst = (sec==0) ? q_out : ((sec==1) ? k_out : v_out);
      const float bv = bias[col];
      #pragma unroll
      for (int MF=0; MF<8; ++MF)
        #pragma unroll
        for (int ri=0; ri<4; ++ri){
          const int row = m0 + wm*128 + MF*16 + (g<<2) + ri;
          const int bb = row>>10, qp = row&1023;
          dst[(((size_t)(bb*16+hhd)*1024 + qp)<<7) + dd] = (bf16)(acc[MF][NF][ri] + bv);
        }
    }
  } else {
    #pragma unroll
    for (int NF=0; NF<4; ++NF){
      const int col = n0 + wn*64 + NF*16 + c;
      const float bv = bias[col];
      #pragma unroll
      for (int MF=0; MF<8; ++MF)
        #pragma unroll
        for (int ri=0; ri<4; ++ri){
          const int row = m0 + wm*128 + MF*16 + (g<<2) + ri;
          c_out[(size_t)row*N + col] = acc[MF][NF][ri] + bv;
        }
    }
  }
}

// ---------------- fused paged + causal flash attention (unchanged from round 5) ----------------
__global__ __launch_bounds__(512) __attribute__((amdgpu_waves_per_eu(4,4))) void k_attn(
    const bf16* __restrict__ qb, const bf16* __restrict__ kb, const bf16* __restrict__ vb,
    const bf16* __restrict__ kpb, const bf16* __restrict__ vpb,
    const int* __restrict__ page_pos, const int* __restrict__ input_pos,
    bf16* __restrict__ ctx)
{
  __shared__ bf16 Ks[2*64*128];
  __shared__ bf16 Vs[2*64*128];
  const int t = threadIdx.x, w = t>>6, l = t&63, g = l>>4, c = l&15;
  const int bid = blockIdx.x;
  const int wg = (bid&7)*128 + (bid>>3);
  const int qt = wg & 7, h = (wg>>3)&15, b = wg>>7;
  const int q0w = (qt<<7) + (w<<4);
  const float scale2 = 0.12751743f; // (1/sqrt(128)) * log2(e)
  const size_t bh = (size_t)(b*16 + h);

  const bf16* qptr = qb + (bh<<17);
  bf16x8 qf[4];
  #pragma unroll
  for (int kc=0;kc<4;kc++)
    qf[kc] = *reinterpret_cast<const bf16x8*>(qptr + ((size_t)(q0w + c)<<7) + kc*32 + (g<<3));

  int kOff[2], vOff[2];
  #pragma unroll
  for (int j=0;j<2;j++){
    const int slot = t + (j<<9);
    {
      const int a = slot<<4; const int r = a>>8; const int co = (a&255) ^ ((r&7)<<4);
      kOff[j] = (r<<7) + (co>>1);
    }
    {
      const int s_ = slot;
      const int p  = ((s_>>6)<<2) | ((s_>>1)&3);
      const int d0 = (((s_>>3)&7)<<4) | ((s_&1)<<3);
      const int pp = (p&32) | ((p&4)<<2) | (((p>>3)&3)<<2) | (p&3); // pi(p)
      vOff[j] = (pp<<7) + d0;
    }
  }
  const bf16* kcb = kb + (bh<<17);
  const bf16* vcb = vb + (bh<<17);
  const int len_b = input_pos[b*2+1];
  const int NT = 32 + ((qt+1)<<1);

  f32x4 o[8] = {};
  float mrow = -1e38f;
  float lsum = 0.f;

  auto tsrc = [&](int T, const bf16*& ks, const bf16*& vs_){
    if (T < 32){
      size_t pb = ((((size_t)(T>>2)<<3) + (size_t)b)*16 + (size_t)h) << 15;
      size_t off = (size_t)(T&3)<<13;
      ks = kpb + pb + off; vs_ = vpb + pb + off;
    } else {
      int kt = T-32; ks = kcb + ((size_t)kt<<13); vs_ = vcb + ((size_t)kt<<13);
    }
  };
  auto stage = [&](int T, int buf){
    const bf16 *ks, *vs_; tsrc(T, ks, vs_);
    char* kd = (char*)Ks + (buf<<14) + (w<<10);
    char* vd = (char*)Vs + (buf<<14) + (w<<10);
    #pragma unroll
    for (int j=0;j<2;j++){
      GLOAD16(ks  + kOff[j], kd + (j<<13));
      GLOAD16(vs_ + vOff[j], vd + (j<<13));
    }
  };

  auto process = [&](int buf, int lo, int hi, bool masked, bool causal, int ktg){
    const char* Kb = (const char*)Ks + (buf<<14);
    const char* Vb = (const char*)Vs + (buf<<14);
    f32x4 s[4] = {};
    #pragma unroll
    for (int kc=0;kc<4;kc++){
      bf16x8 kf[4];
      #pragma unroll
      for (int cb=0;cb<4;cb++){
        const int krow = (cb<<4) + c;
        unsigned a = (unsigned)((krow<<8) + (kc<<6) + (g<<4)); a ^= (unsigned)((krow&7)<<4);
        kf[cb] = *reinterpret_cast<const bf16x8*>(Kb + a);
      }
      __builtin_amdgcn_s_setprio(1);
      #pragma unroll
      for (int cb=0;cb<4;cb++)
        s[cb] = __builtin_amdgcn_mfma_f32_16x16x32_bf16(kf[cb], qf[kc], s[cb], 0,0,0);
      __builtin_amdgcn_s_setprio(0);
    }
    if (masked){
      #pragma unroll
      for (int cb=0;cb<4;cb++)
        #pragma unroll
        for (int ri=0;ri<4;ri++){
          const int kvl = (cb<<4) + (g<<2) + ri;
          bool ok = (kvl >= lo) && (kvl < hi);
          if (causal) ok = ok && ((ktg + kvl) <= (q0w + c));
          s[cb][ri] = ok ? s[cb][ri]*scale2 : -3e38f;
        }
    } else {
      #pragma unroll
      for (int cb=0;cb<4;cb++)
        #pragma unroll
        for (int ri=0;ri<4;ri++)
          s[cb][ri] *= scale2;
    }
    {
      float mx = -3e38f;
      #pragma unroll
      for (int cb=0;cb<4;cb++)
        #pragma unroll
        for (int ri=0;ri<4;ri++) mx = fmaxf(mx, s[cb][ri]);
      mx = fmaxf(mx, __shfl_xor(mx, 16, 64));
      mx = fmaxf(mx, __shfl_xor(mx, 32, 64));
      const int defer = __all(mx - mrow <= 11.5f);
      if (!defer){
        const float mn = fmaxf(mrow, mx);
        const float al = exp2f(mrow - mn);
        mrow = mn;
        lsum *= al;
        #pragma unroll
        for (int ri=0;ri<4;ri++){
          const float av = __shfl(al, (l&48) | ((g<<2)+ri), 64);
          #pragma unroll
          for (int dcb=0;dcb<8;dcb++) o[dcb][ri] *= av;
        }
      }
      float ps = 0.f;
      #pragma unroll
      for (int cb=0;cb<4;cb++)
        #pragma unroll
        for (int ri=0;ri<4;ri++){
          const float e = exp2f(s[cb][ri] - mrow);
          s[cb][ri] = e; ps += e;
        }
      lsum += ps;
    }
    #pragma unroll
    for (int kc=0;kc<2;kc++){
      u16x4 vr0[8], vr1[8];
      #pragma unroll
      for (int dcb=0;dcb<8;dcb++){
        const unsigned sub = ((unsigned)((((kc<<3) + (g<<1))<<3) + dcb)<<7) + ((unsigned)c<<3);
        as3_void* pl = (as3_void*)(Vb + sub);
        asm volatile("ds_read_b64_tr_b16 %0, %2 offset:0\n\t"
                     "ds_read_b64_tr_b16 %1, %2 offset:1024"
                     : "=&v"(vr0[dcb]), "=&v"(vr1[dcb]) : "v"(pl) : "memory");
      }
      bf16x8 pav;
      #pragma unroll
      for (int e=0;e<8;e++)
        pav[e] = (bf16)s[(kc<<1)+(e>>2)][e&3];
      asm volatile("s_waitcnt lgkmcnt(0)" ::: "memory");
      __builtin_amdgcn_sched_barrier(0);
      __builtin_amdgcn_s_setprio(1);
      #pragma unroll
      for (int dcb=0;dcb<8;dcb++){
        union { unsigned short us[8]; bf16x8 v; } uu;
        #pragma unroll
        for (int i=0;i<4;i++){ uu.us[i]=vr0[dcb][i]; uu.us[4+i]=vr1[dcb][i]; }
        o[dcb] = __builtin_amdgcn_mfma_f32_16x16x32_bf16(pav, uu.v, o[dcb], 0,0,0);
      }
      __builtin_amdgcn_s_setprio(0);
    }
  };

  int buf = 0;
  stage(0, 0);
  asm volatile("s_waitcnt vmcnt(0)" ::: "memory");
  __syncthreads();
  for (int T=0; T<NT; ++T){
    if (T+1 < NT) stage(T+1, buf^1);
    int lo=0, hi=64, ktg=0; bool causal=false, masked=false, skip=false;
    if (T < 32){
      const int pg = T>>2, to = T&3;
      const int start = page_pos[(pg*8+b)*2], plen = page_pos[(pg*8+b)*2+1];
      lo = start - (to<<6); hi = start + plen - (to<<6); if (hi>64) hi=64;
      masked = (lo > 0) || (hi < 64);
      skip = (hi <= 0) || (lo >= 64);
    } else {
      const int kt = T-32; ktg = kt<<6;
      hi = len_b - ktg; if (hi>64) hi=64;
      skip = (ktg > q0w + 15) || (hi <= 0);
      causal = (ktg + 63 > q0w);
      masked = causal || (hi < 64);
    }
    if (!skip) process(buf, lo, hi, masked, causal, ktg);
    asm volatile("s_waitcnt vmcnt(0)" ::: "memory");
    __syncthreads();
    buf ^= 1;
  }

  {
    float tl = lsum;
    tl += __shfl_xor(tl, 16, 64);
    tl += __shfl_xor(tl, 32, 64);
    const float inv = 1.f / fmaxf(tl, 1e-9f);
    #pragma unroll
    for (int ri=0;ri<4;ri++){
      const float iv = __shfl(inv, (l&48) | ((g<<2)+ri), 64);
      const int q = q0w + (g<<2) + ri;
      #pragma unroll
      for (int dcb=0;dcb<8;dcb++)
        ctx[(((size_t)(b<<10) + q)<<11) + (h<<7) + (dcb<<4) + c] = (bf16)(o[dcb][ri]*iv);
    }
  }
}

// ---------------- launcher ----------------
extern "C" void kernel_launch(void* const* d_in, const int* in_sizes, int n_in,
                              void* d_out, int out_size, void* d_ws, size_t ws_size,
                              hipStream_t stream)
{
  const float* hidden  = (const float*)d_in[0];
  const float* W_attn  = (const float*)d_in[1];
  const float* b_attn  = (const float*)d_in[2];
  const float* W_proj  = (const float*)d_in[3];
  const float* b_proj  = (const float*)d_in[4];
  const float* k_pages = (const float*)d_in[5];
  const float* v_pages = (const float*)d_in[6];
  const int*   page_pos  = (const int*)d_in[7];
  const int*   input_pos = (const int*)d_in[8];
  float* out = (float*)d_out;
  char* ws = (char*)d_ws;
  bf16* A1  = (bf16*)(ws);              // 8192x2048 bf16 (32MB); reused as ctx
  bf16* Wt1 = (bf16*)(ws + 33554432);   // 6144x2048 bf16 (24MB)
  bf16* Wt2 = (bf16*)(ws + 58720256);   // 2048x2048 bf16 (8MB)
  bf16* qb  = (bf16*)(ws + 67108864);   // [8,16,1024,128] bf16 (32MB)
  bf16* kb  = (bf16*)(ws + 100663296);
  bf16* vb  = (bf16*)(ws + 134217728);
  bf16* kpb = (bf16*)(ws + 167772160);  // bf16 pages (64MB)
  bf16* vpb = (bf16*)(ws + 234881024);  // bf16 pages (64MB); end 301,989,888
  bf16* ctx = A1;

  k_cvt_bf16<<<16384, 256, 0, stream>>>(hidden, A1, 4194304);
  k_cvt_bf16<<<32768, 256, 0, stream>>>(k_pages, kpb, 8388608);
  k_cvt_bf16<<<32768, 256, 0, stream>>>(v_pages, vpb, 8388608);
  k_transpose_cvt<<<dim3(192,64), 256, 0, stream>>>(W_attn, Wt1, 2048, 6144);
  k_transpose_cvt<<<dim3(64,64),  256, 0, stream>>>(W_proj, Wt2, 2048, 2048);
  k_gemm8<0><<<768, 512, 0, stream>>>(A1, Wt1, b_attn, 6144, 2048, qb, kb, vb, nullptr);
  k_attn<<<1024, 512, 0, stream>>>(qb, kb, vb, kpb, vpb, page_pos, input_pos, ctx);
  k_gemm8<1><<<256, 512, 0, stream>>>(ctx, Wt2, b_proj, 2048, 2048, nullptr, nullptr, nullptr, out);
}